// Round 7
// baseline (1243.351 us; speedup 1.0000x reference)
//
#include <hip/hip_runtime.h>

// ---------------------------------------------------------------------------
// MultiDimensionalLSTM on MI355X.
// B=32, C=32, Y=X=128, win 4x4 -> grid 32x32 cells, F=512, R=128, gates 5R=640.
// Input projection: one split-bf16 MFMA GEMM (3-term, fp32-quality, 91 us).
// Recurrence: ONE persistent kernel, 32 WGs = one grid-ROW each (8 waves).
// LEFT dep WG-internal (h via LDS, c in regs), computed BEFORE the up-wait.
// UP dep: h/c published via RETURNING atomic swaps (returns prove MALL
// commitment), then relaxed flag. No buffer_wbl2 (R5: 11us/hop), no
// buffer_inv (R3: 2.1ms).
// PRECISION (R6 post-mortem): recurrent GEMM in f16 single-plane -- W error
// is systematic across the 62-deep chain, bf16-hi-only accumulated to 1.8e-2;
// f16's 10 mantissa bits cut it 8x. c fp32; h published as f16.
// ---------------------------------------------------------------------------

typedef unsigned short u16;
typedef unsigned int u32;
typedef unsigned long long u64;
typedef _Float16 f16;
typedef __attribute__((ext_vector_type(8))) short short8;      // 8 bf16
typedef __attribute__((ext_vector_type(8))) _Float16 half8;    // 8 f16
typedef __attribute__((ext_vector_type(8))) unsigned short us8;
typedef __attribute__((ext_vector_type(4))) float floatx4;

union FragH { u64 q[2]; half8 s; };
union HU { f16 f; u16 u; };

__device__ inline u16 f2bf(float f) {               // RNE fp32 -> bf16
  unsigned u = __float_as_uint(f);
  u += 0x7fffu + ((u >> 16) & 1u);
  return (u16)(u >> 16);
}
__device__ inline float bf2f(u16 v) { return __uint_as_float(((unsigned)v) << 16); }
__device__ inline u16 f2h_bits(float f) { HU h; h.f = (f16)f; return h.u; }  // RNE

__device__ inline void async16(u16* lds, const u16* g) {
  __builtin_amdgcn_global_load_lds((const __attribute__((address_space(1))) void*)g,
                                   (__attribute__((address_space(3))) void*)lds, 16, 0, 0);
}

__device__ inline float sigf(float x) { return 1.f / (1.f + __expf(-x)); }
__device__ inline float tanh_fast(float x) { return 1.f - 2.f / (__expf(2.f * x) + 1.f); }

__device__ inline void waitflag(const int* f, int target) {
  while (__hip_atomic_load(f, __ATOMIC_RELAXED, __HIP_MEMORY_SCOPE_AGENT) < target)
    __builtin_amdgcn_s_sleep(1);
  __asm__ __volatile__("" ::: "memory");
}
__device__ inline u64 aload64(const u64* p) {
  return __hip_atomic_load(p, __ATOMIC_RELAXED, __HIP_MEMORY_SCOPE_AGENT);
}
__device__ inline u64 aswap64(u64* p, u64 v) {   // RETURNING swap: ack = at MALL
  return __hip_atomic_exchange(p, v, __ATOMIC_RELAXED, __HIP_MEMORY_SCOPE_AGENT);
}
__device__ inline void astore32(u32* p, u32 v) {
  __hip_atomic_store(p, v, __ATOMIC_RELAXED, __HIP_MEMORY_SCOPE_AGENT);
}

// ---------------------------------------------------------------------------
// Prep 1: W [768][640] fp32 -> WxT_{h,l} bf16 [640][512] (input GEMM, split),
// WhT16 f16 [640][256] (recurrent GEMM), biasp [640].
// pcol = r*5+g <-> orig col g*128+r. WhT row k: k<128 -> W row 512+k (up h1),
// k>=128 -> W row 640+(k-128) (left h2).
// ---------------------------------------------------------------------------
__global__ __launch_bounds__(256) void k_wprep(const float* __restrict__ W,
                                               const float* __restrict__ bias,
                                               u16* __restrict__ WxT_h, u16* __restrict__ WxT_l,
                                               f16* __restrict__ WhT16,
                                               float* __restrict__ biasp) {
  int pcol = blockIdx.x;
  int col  = (pcol % 5) * 128 + pcol / 5;
  for (int k = threadIdx.x; k < 768; k += 256) {
    float v = W[(size_t)k * 640 + col];
    if (k < 512) {
      u16 hi = f2bf(v);
      WxT_h[(size_t)pcol * 512 + k] = hi;
      WxT_l[(size_t)pcol * 512 + k] = f2bf(v - bf2f(hi));
    } else {
      WhT16[(size_t)pcol * 256 + (k - 512)] = (f16)v;   // RNE
    }
  }
  if (threadIdx.x == 0) biasp[pcol] = bias[col];
}

// ---------------------------------------------------------------------------
// Prep 2: gather x -> xs hi/lo [t][b][f]; xs[t][b][f]=x[b][f&31][t>>3][(t&7)*16+(f>>5)]
// ---------------------------------------------------------------------------
__global__ __launch_bounds__(256) void k_xgather(const float* __restrict__ x,
                                                 u16* __restrict__ xs_h,
                                                 u16* __restrict__ xs_l) {
  int lane = threadIdx.x & 63;
  int pair = blockIdx.x * 4 + (threadIdx.x >> 6);
  int t = pair >> 5, b = pair & 31;
  int y = t >> 3, x0 = (t & 7) * 16;
  int j = lane >> 2;
  int cbase = (lane & 3) * 8;
  const float* src = x + ((size_t)b * 32 * 128 + y) * 128 + x0 + j;
  us8 vh, vl;
#pragma unroll
  for (int u = 0; u < 8; ++u) {
    float f = src[(size_t)(cbase + u) * 16384];
    u16 hi = f2bf(f);
    vh[u] = hi;
    vl[u] = f2bf(f - bf2f(hi));
  }
  *(us8*)(xs_h + (size_t)pair * 512 + lane * 8) = vh;
  *(us8*)(xs_l + (size_t)pair * 512 + lane * 8) = vl;
}

// ---------------------------------------------------------------------------
// Input GEMM (split-bf16, 3-term): M=32768, N=640, K=512. 128x128 tile, BK=32.
// ---------------------------------------------------------------------------
__global__ __launch_bounds__(256) void k_gemm_in(const u16* __restrict__ xs_h,
                                                 const u16* __restrict__ xs_l,
                                                 const u16* __restrict__ WxT_h,
                                                 const u16* __restrict__ WxT_l,
                                                 const float* __restrict__ biasp,
                                                 float* __restrict__ Gp) {
  __shared__ u16 Ah[128 * 32], Al[128 * 32];
  __shared__ u16 Bh[128 * 32], Bl[128 * 32];
  const int tid = threadIdx.x;
  const int wv = tid >> 6, lane = tid & 63;
  const int quad = lane >> 4, l16 = lane & 15;
  const int m0 = blockIdx.x * 128;
  const int n0 = blockIdx.y * 128;
  const int arow = lane >> 2;
  const int acol = (lane & 3) * 8;

  floatx4 acc[4][4] = {};

  for (int kt = 0; kt < 512; kt += 32) {
#pragma unroll
    for (int i = 0; i < 2; ++i) {
      int chunk = wv * 2 + i;
      int row = chunk * 16 + arow;
      size_t aoff = (size_t)(m0 + row) * 512 + kt + acol;
      size_t boff = (size_t)(n0 + row) * 512 + kt + acol;
      async16(&Ah[chunk * 512 + lane * 8], xs_h + aoff);
      async16(&Al[chunk * 512 + lane * 8], xs_l + aoff);
      async16(&Bh[chunk * 512 + lane * 8], WxT_h + boff);
      async16(&Bl[chunk * 512 + lane * 8], WxT_l + boff);
    }
    __syncthreads();
    short8 afh[4], afl[4], bfh[4], bfl[4];
#pragma unroll
    for (int mt = 0; mt < 4; ++mt) {
      int ro = ((wv & 1) * 64 + mt * 16 + l16) * 32 + quad * 8;
      afh[mt] = *(const short8*)&Ah[ro];
      afl[mt] = *(const short8*)&Al[ro];
    }
#pragma unroll
    for (int nt = 0; nt < 4; ++nt) {
      int ro = ((wv >> 1) * 64 + nt * 16 + l16) * 32 + quad * 8;
      bfh[nt] = *(const short8*)&Bh[ro];
      bfl[nt] = *(const short8*)&Bl[ro];
    }
#pragma unroll
    for (int mt = 0; mt < 4; ++mt)
#pragma unroll
      for (int nt = 0; nt < 4; ++nt) {
        floatx4 a = acc[mt][nt];
        a = __builtin_amdgcn_mfma_f32_16x16x32_bf16(afl[mt], bfh[nt], a, 0, 0, 0);
        a = __builtin_amdgcn_mfma_f32_16x16x32_bf16(afh[mt], bfl[nt], a, 0, 0, 0);
        a = __builtin_amdgcn_mfma_f32_16x16x32_bf16(afh[mt], bfh[nt], a, 0, 0, 0);
        acc[mt][nt] = a;
      }
    __syncthreads();
  }
#pragma unroll
  for (int nt = 0; nt < 4; ++nt) {
    int n = n0 + (wv >> 1) * 64 + nt * 16 + l16;
    float bv = biasp[n];
#pragma unroll
    for (int mt = 0; mt < 4; ++mt) {
      int m = m0 + (wv & 1) * 64 + mt * 16 + quad * 4;
#pragma unroll
      for (int r = 0; r < 4; ++r)
        Gp[(size_t)(m + r) * 640 + n] = acc[mt][nt][r] + bv;
    }
  }
}

// ---------------------------------------------------------------------------
// Persistent recurrence: grid 32 (one WG per grid-row h), block 512 (8 waves).
// Wave wv owns pcols [wv*80, wv*80+80) == r in [wv*16, wv*16+16), all 32 b.
// f16 single-plane A (h) and B (WhT16); c fp32 via sc1 u64 pairs.
// Left-half MFMAs run BEFORE the up-wait (off critical path).
// ---------------------------------------------------------------------------
__global__ __launch_bounds__(512, 2) void k_rec(const f16* __restrict__ WhT,
                                                const float* __restrict__ Gp,
                                                u64* __restrict__ cbuf,    // fp32[1024][32][128] as u64
                                                u64* __restrict__ hbf,     // f16 [1024][32][128] as u64
                                                float* __restrict__ out,
                                                int* __restrict__ flags,
                                                u64* __restrict__ dummy) {
  __shared__ float Gs[8 * 16 * 81];     // 41472 B: per-wave 16b x 81 (pad) gate buf
  __shared__ u16 HLh[32][136];          // 8704 B: h_left f16 bits [b][r], pad 128->136
  const int h = blockIdx.x;
  const int tid = threadIdx.x;
  const int wv = tid >> 6, lane = tid & 63;
  const int quad = lane >> 4, l16 = lane & 15;
  float* Gw = &Gs[wv * 16 * 81];
  const int eb16 = lane & 15;           // epilogue b within 16
  const int err0 = (lane >> 4) * 4;     // epilogue r offset within wave's 16
  const int rg = wv * 16 + err0;

  float cl[2][4] = {{0, 0, 0, 0}, {0, 0, 0, 0}};   // c_left per phase
  u64 xsacc = 0;                                   // xor-consume of swap returns

  for (int w = 0; w < 32; ++w) {
    const int t = h * 32 + w;
    const bool upok = t > 32;            // faithful off-by-one: (1,0) gets no up
    const bool leftok = w > 0;

    // --- left A-frags from LDS (previous cell, this WG) ---
    FragH lh[2][4];
    if (leftok) {
#pragma unroll
      for (int mt = 0; mt < 2; ++mt)
#pragma unroll
        for (int ks = 0; ks < 4; ++ks)
          lh[mt][ks].s = *(const half8*)&HLh[mt * 16 + l16][ks * 32 + quad * 8];
    }
    __syncthreads();   // B1: left reads done -> epilogue HL writes safe

    floatx4 acc[2][5] = {};
    const f16* brow = WhT + (size_t)(wv * 80 + l16) * 256 + quad * 8;

    // --- left-half MFMAs (k in [128,256)) -- no up dependency ---
    if (leftok) {
#pragma unroll
      for (int ks = 0; ks < 4; ++ks)
#pragma unroll
        for (int nt = 0; nt < 5; ++nt) {
          half8 bh = *(const half8*)(brow + (size_t)nt * 16 * 256 + 128 + ks * 32);
#pragma unroll
          for (int mt = 0; mt < 2; ++mt)
            acc[mt][nt] = __builtin_amdgcn_mfma_f32_16x16x32_f16(lh[mt][ks].s, bh, acc[mt][nt], 0, 0, 0);
        }
    }

    // --- Gp prefetch (plain loads; layout matches epilogue lanes) ---
    float gpre[2][20];
#pragma unroll
    for (int p = 0; p < 2; ++p) {
      const float* gsrc = Gp + ((size_t)t * 32 + p * 16 + eb16) * 640 + wv * 80 + err0 * 5;
#pragma unroll
      for (int j = 0; j < 5; ++j) {
        floatx4 v = *(const floatx4*)(gsrc + j * 4);
        gpre[p][j * 4 + 0] = v[0]; gpre[p][j * 4 + 1] = v[1];
        gpre[p][j * 4 + 2] = v[2]; gpre[p][j * 4 + 3] = v[3];
      }
    }

    // --- up half: wait, MALL loads, MFMAs (k in [0,128)) ---
    float cu[2][4] = {{0, 0, 0, 0}, {0, 0, 0, 0}};
    if (upok) {
      waitflag(&flags[t - 32], 1);
      FragH uh[2][4];
#pragma unroll
      for (int mt = 0; mt < 2; ++mt)
#pragma unroll
        for (int ks = 0; ks < 4; ++ks) {
          size_t fi = (((size_t)(t - 32) * 32 + mt * 16 + l16) * 128 + ks * 32 + quad * 8) >> 2;
          uh[mt][ks].q[0] = aload64(hbf + fi);
          uh[mt][ks].q[1] = aload64(hbf + fi + 1);
        }
#pragma unroll
      for (int p = 0; p < 2; ++p) {
        size_t ci = (((size_t)(t - 32) * 32 + p * 16 + eb16) * 128 + rg) >> 1;
        u64 a = aload64(cbuf + ci), b2 = aload64(cbuf + ci + 1);
        cu[p][0] = __uint_as_float((u32)a);
        cu[p][1] = __uint_as_float((u32)(a >> 32));
        cu[p][2] = __uint_as_float((u32)b2);
        cu[p][3] = __uint_as_float((u32)(b2 >> 32));
      }
#pragma unroll
      for (int ks = 0; ks < 4; ++ks)
#pragma unroll
        for (int nt = 0; nt < 5; ++nt) {
          half8 bh = *(const half8*)(brow + (size_t)nt * 16 * 256 + ks * 32);
#pragma unroll
          for (int mt = 0; mt < 2; ++mt)
            acc[mt][nt] = __builtin_amdgcn_mfma_f32_16x16x32_f16(uh[mt][ks].s, bh, acc[mt][nt], 0, 0, 0);
        }
    }

    // --- epilogue per m-tile phase (same-wave LDS transpose via Gw) ---
#pragma unroll
    for (int p = 0; p < 2; ++p) {
#pragma unroll
      for (int nt = 0; nt < 5; ++nt)
#pragma unroll
        for (int r = 0; r < 4; ++r)
          Gw[(quad * 4 + r) * 81 + nt * 16 + l16] = acc[p][nt][r];
      const int b = p * 16 + eb16;
      float nh[4], nc[4];
#pragma unroll
      for (int i = 0; i < 4; ++i) {
        const float* gq = &Gw[eb16 * 81 + (err0 + i) * 5];
        float gi = gq[0] + gpre[p][i * 5 + 0];
        float gj = gq[1] + gpre[p][i * 5 + 1];
        float g1 = gq[2] + gpre[p][i * 5 + 2];
        float g2 = gq[3] + gpre[p][i * 5 + 3];
        float go = gq[4] + gpre[p][i * 5 + 4];
        float c2 = leftok ? cl[p][i] : 0.f;
        nc[i] = cu[p][i] * sigf(g1) + c2 * sigf(g2) + sigf(gi) * tanh_fast(gj);
        nh[i] = tanh_fast(nc[i]) * sigf(go);
        cl[p][i] = nc[i];
      }
      // pack h as 4x f16
      u64 hq = 0;
#pragma unroll
      for (int i = 0; i < 4; ++i) hq |= (u64)f2h_bits(nh[i]) << (16 * i);
      // LDS h_left for next cell
      *(u64*)&HLh[b][rg] = hq;
      // global publish via RETURNING swaps (proof of MALL commitment)
      size_t hflat = ((size_t)t * 32 + b) * 128 + rg;
      xsacc ^= aswap64(hbf + (hflat >> 2), hq);
      u64 c01 = (u64)__float_as_uint(nc[0]) | ((u64)__float_as_uint(nc[1]) << 32);
      u64 c23 = (u64)__float_as_uint(nc[2]) | ((u64)__float_as_uint(nc[3]) << 32);
      xsacc ^= aswap64(cbuf + (hflat >> 1), c01);
      xsacc ^= aswap64(cbuf + (hflat >> 1) + 1, c23);
      // output (plain cached store; no wbl2 anywhere, dirty L2 is fine)
      floatx4 ov; ov[0] = nh[0]; ov[1] = nh[1]; ov[2] = nh[2]; ov[3] = nh[3];
      *(floatx4*)(out + (((size_t)b * 32 + h) * 32 + w) * 128 + rg) = ov;
    }

    if (xsacc == 0x9e3779b97f4a7c15ull) dummy[tid] = xsacc;  // never true: forces waits
    __syncthreads();   // B2: all waves' swap returns drained + HL visible
    if (tid == 0) astore32((u32*)&flags[t], 1u);  // relaxed: data already at MALL
  }
}

// ---------------------------------------------------------------------------
extern "C" void kernel_launch(void* const* d_in, const int* in_sizes, int n_in,
                              void* d_out, int out_size, void* d_ws, size_t ws_size,
                              hipStream_t stream) {
  const float* x    = (const float*)d_in[0];   // [32,32,128,128]
  const float* W    = (const float*)d_in[1];   // [768,640]
  const float* bias = (const float*)d_in[2];   // [640]
  float* out = (float*)d_out;                  // [32,32,32,128]
  char* ws = (char*)d_ws;

  size_t off = 0;
  u16*   xs_h  = (u16*)(ws + off);  off += (size_t)32768 * 512 * 2;  // 33.6 MB
  u16*   xs_l  = (u16*)(ws + off);  off += (size_t)32768 * 512 * 2;  // 33.6 MB
  u16*   WxT_h = (u16*)(ws + off);  off += (size_t)640 * 512 * 2;
  u16*   WxT_l = (u16*)(ws + off);  off += (size_t)640 * 512 * 2;
  f16*   WhT16 = (f16*)(ws + off);  off += (size_t)640 * 256 * 2;
  float* biasp = (float*)(ws + off); off += (size_t)640 * 4;
  float* Gp    = (float*)(ws + off); off += (size_t)32768 * 640 * 4; // 83.9 MB
  u64*   cbuf  = (u64*)(ws + off);  off += (size_t)32768 * 128 * 4;  // 16.8 MB
  u64*   hbf   = (u64*)(ws + off);  off += (size_t)32768 * 128 * 2;  // 8.4 MB
  int*   flags = (int*)(ws + off);  off += 1024 * 4;
  u64*   dummy = (u64*)(ws + off);  off += 512 * 8;
  (void)ws_size;

  hipMemsetAsync(flags, 0, 1024 * sizeof(int), stream);
  k_wprep<<<dim3(640), dim3(256), 0, stream>>>(W, bias, WxT_h, WxT_l, WhT16, biasp);
  k_xgather<<<dim3(8192), dim3(256), 0, stream>>>(x, xs_h, xs_l);
  k_gemm_in<<<dim3(256, 5), dim3(256), 0, stream>>>(xs_h, xs_l, WxT_h, WxT_l, biasp, Gp);
  k_rec<<<dim3(32), dim3(512), 0, stream>>>(WhT16, Gp, cbuf, hbf, out, flags, dummy);
}